// Round 9
// baseline (247.967 us; speedup 1.0000x reference)
//
#include <hip/hip_runtime.h>
#include <hip/hip_bf16.h>
#include <stdint.h>
#include <stddef.h>

// Problem: B=2, L=2048, D=1024, H=16, HD=64.
// Inputs FP32, output FP32.  Internal pipeline bf16 MFMA.
// R21: attn triple-buffered K/V/bias with ONE-TILE-AHEAD fragment preload:
// kf (4x ds_read_b128) + bias (16x ds_read_b32) for tile t+1 are issued
// DURING compute(t) -- possible only with 3 buffers (t+1's buffer was
// published a barrier ago and isn't overwritten until t+1).  QK's lgkm
// head-wait disappears.  Frag sets ping-pong A/B via 2-tile unroll (no
// runtime reg indexing).  exp2 in-place in st (saves 16 VGPR).
// LDS 38.4->57.6KB, still 2 blocks/CU (grid-capped).
// R20: cvt_pk_bf16 + permlane32_swap P-assembly (54.8us best).
// R17: 512-thread / 8-wave blocks, Q-tile 128 rows per staged K/V tile.
// R14: kw key-split + LDS reduce, bias as MFMA C-init; gemm 128x64 BK=64
// (best measured; R15/R18 restructures both regressed).
// R13: prefetch pipeline, one barrier/tile, exp2 with folded log2e.

#define NB     2
#define NH     16
#define SL     2048
#define DH     64
#define DMODEL 1024
#define SCP    4096   // padded scores row stride (floats); 4095 real
#define LOG2E  1.44269504088896340736f

typedef __attribute__((ext_vector_type(8)))  short bf16x8;
typedef __attribute__((ext_vector_type(4)))  short bf16x4;
typedef __attribute__((ext_vector_type(4)))  float f32x4;
typedef __attribute__((ext_vector_type(16))) float f32x16;

static __device__ __forceinline__ short f2bf(float x) {   // RNE
  __hip_bfloat16 h = __float2bfloat16(x);
  return *reinterpret_cast<short*>(&h);
}
static __device__ __forceinline__ short f2bf_fast(float x) {  // round-half-up
  union { float f; uint32_t u; } v; v.f = x;
  return (short)((v.u + 0x8000u) >> 16);
}
static __device__ __forceinline__ float fexp2(float x) {
#if __has_builtin(__builtin_amdgcn_exp2f)
  return __builtin_amdgcn_exp2f(x);
#else
  return __expf(x * 0.69314718056f);
#endif
}
static __device__ __forceinline__ uint32_t cvtpk_bf16(float lo, float hi) {
  uint32_t r;
  asm("v_cvt_pk_bf16_f32 %0, %1, %2" : "=v"(r) : "v"(lo), "v"(hi));
  return r;
}
// swaps a's upper-32 lanes with b's lower-32 lanes (CDNA4)
#define PLSWAP(a, b) asm("v_permlane32_swap_b32 %0, %1" : "+v"(a), "+v"(b))

#define GLD(g, l) __builtin_amdgcn_global_load_lds( \
    (const __attribute__((address_space(1))) void*)(g), \
    (__attribute__((address_space(3))) void*)(l), 16, 0, 0)

// ---------------------------------------------------- prep: cvt x, cvt w, bias
__global__ __launch_bounds__(256) void prep_k(
    const float* __restrict__ x, const float* __restrict__ w,
    const float* __restrict__ koff, const float* __restrict__ kamp,
    const float* __restrict__ kshp,
    short* __restrict__ xbf, short* __restrict__ wbf,
    float* __restrict__ scores) {
  const int bx = blockIdx.x, tid = threadIdx.x;
  if (bx < 3584) {
    const float* src = (bx < 2048) ? x : w;
    short* dst       = (bx < 2048) ? xbf : wbf;
    const size_t i   = ((size_t)(bx < 2048 ? bx : bx - 2048) * 256 + tid) * 8;
    float4 a = *(const float4*)(src + i);
    float4 b = *(const float4*)(src + i + 4);
    bf16x8 o;
    o[0] = f2bf(a.x); o[1] = f2bf(a.y); o[2] = f2bf(a.z); o[3] = f2bf(a.w);
    o[4] = f2bf(b.x); o[5] = f2bf(b.y); o[6] = f2bf(b.z); o[7] = f2bf(b.w);
    *(bf16x8*)(dst + i) = o;
  } else {
    const int idx = bx - 3584;
    const int h = idx >> 4;
    const int r = (idx & 15) * 256 + tid;
    if (r >= 4095) return;
    float rel = (float)(r - (SL - 1));
    float acc = 0.f;
#pragma unroll
    for (int k = 0; k < 16; ++k) {
      float o = koff[h * 16 + k];
      float a = kamp[h * 16 + k];
      float s = fabsf(kshp[h * 16 + k]);
      float d = o - rel;
      acc += a * __expf(-s * d * d);
    }
    scores[h * SCP + r] = acc * LOG2E;   // pre-scaled for exp2 in attn
  }
}

// ---------------------------------------------------------------- QKV GEMM
// (verbatim R14/R17 -- best measured config)
__global__ __launch_bounds__(256) void qkv_gemm_k(
    const short* __restrict__ A, const short* __restrict__ Bw,
    __hip_bfloat16* __restrict__ kbuf, __hip_bfloat16* __restrict__ vbufT,
    __hip_bfloat16* __restrict__ qbuf) {
  __shared__ __align__(16) short SM[12288];       // 24 KB; As | Bs, reused by epilogue
  short* As = SM;                                  // 128*64 shorts
  short* Bs = SM + 8192;                           // 64*64 shorts
  const int tid  = threadIdx.x;
  const int lane = tid & 63;
  const int wv   = tid >> 6;
  const int l15  = lane & 15, quad = lane >> 4;
  const int wm = (wv & 1) * 64, wn = (wv >> 1) * 32;
  const int xt = blockIdx.x, yt = blockIdx.y;
  const int m0 = yt * 128, n0 = xt * 64;
  const int which = xt >> 4;                       // 0=k, 1=v, 2=q
  const int hh    = xt & 15;                       // the head this tile serves

  f32x4 acc[4][2];
#pragma unroll
  for (int r = 0; r < 4; ++r)
#pragma unroll
    for (int c = 0; c < 2; ++c) acc[r][c] = (f32x4){0.f, 0.f, 0.f, 0.f};

  for (int kt = 0; kt < 16; ++kt) {
    const int k0 = kt * 64;
#pragma unroll
    for (int it = 0; it < 4; ++it) {               // A: 1024 chunks
      const int e8  = it * 256 + tid;
      GLD(A + (size_t)(m0 + (e8 >> 3)) * DMODEL + k0 + (e8 & 7) * 8, &As[e8 * 8]);
    }
#pragma unroll
    for (int it = 0; it < 2; ++it) {               // B: 512 chunks
      const int e8  = it * 256 + tid;
      GLD(Bw + (size_t)(n0 + (e8 >> 3)) * DMODEL + k0 + (e8 & 7) * 8, &Bs[e8 * 8]);
    }
    __syncthreads();
#pragma unroll
    for (int ki = 0; ki < 64; ki += 32) {
      bf16x8 af[4], bfv[2];
#pragma unroll
      for (int r = 0; r < 4; ++r)
        af[r] = *(const bf16x8*)&As[(wm + r * 16 + l15) * 64 + ki + quad * 8];
#pragma unroll
      for (int c = 0; c < 2; ++c)
        bfv[c] = *(const bf16x8*)&Bs[(wn + c * 16 + l15) * 64 + ki + quad * 8];
#pragma unroll
      for (int r = 0; r < 4; ++r)
#pragma unroll
        for (int c = 0; c < 2; ++c)
          acc[r][c] = __builtin_amdgcn_mfma_f32_16x16x32_bf16(af[r], bfv[c], acc[r][c], 0, 0, 0);
    }
    __syncthreads();
  }

  // ---- epilogue: C/D layout m = wm+r*16+quad*4+g, n = wn+c*16+l15 ----
  const int bb  = m0 >> 11;
  const int llb = m0 & 2047;
  if (which != 1) {
    const float qs = (which == 2) ? 0.125f * LOG2E : 1.0f;  // log2e folded into q
#pragma unroll
    for (int r = 0; r < 4; ++r)
#pragma unroll
      for (int c = 0; c < 2; ++c)
#pragma unroll
        for (int gg = 0; gg < 4; ++gg)
          SM[(wm + r * 16 + quad * 4 + gg) * 72 + wn + c * 16 + l15] =
              f2bf_fast(acc[r][c][gg] * qs);
    __syncthreads();
    __hip_bfloat16* dst = (which == 0) ? kbuf : qbuf;
#pragma unroll
    for (int i = 0; i < 4; ++i) {
      const int cidx = i * 256 + tid;              // 1024 16B chunks
      const int m = cidx >> 3, ch = cidx & 7;
      bf16x8 val = *(const bf16x8*)&SM[m * 72 + ch * 8];
      *(bf16x8*)&dst[(((size_t)bb * NH + hh) * SL + llb + m) * DH + ch * 8] = val;
    }
  } else {
#pragma unroll
    for (int r = 0; r < 4; ++r)
#pragma unroll
      for (int c = 0; c < 2; ++c) {
        bf16x4 pk;
#pragma unroll
        for (int gg = 0; gg < 4; ++gg) pk[gg] = f2bf_fast(acc[r][c][gg]);
        *(bf16x4*)&SM[(wn + c * 16 + l15) * 136 + wm + r * 16 + quad * 4] = pk;
      }
    __syncthreads();
#pragma unroll
    for (int i = 0; i < 4; ++i) {
      const int cidx = i * 256 + tid;              // 1024 16B chunks
      const int n = cidx >> 4, ch = cidx & 15;
      bf16x8 val = *(const bf16x8*)&SM[n * 136 + ch * 8];
      *(bf16x8*)&vbufT[(((size_t)bb * NH + hh) * DH + n) * SL + llb + ch * 8] = val;
    }
  }
}

// ---------------------------------------------------------------- attention
// R21: triple-buffered tiles + ping-pong fragment preload (kf+bias one tile
// ahead, loaded during compute).  R20 P-assembly (cvt_pk + permlane32_swap).
// LDS: Ks 3x9216 + Vs 3x9216 + Bt 3x768B = 57.6 KB; 2 blocks/CU x 8 waves.
__global__ __launch_bounds__(512, 4) void attn_k(
    const __hip_bfloat16* __restrict__ qbuf, const __hip_bfloat16* __restrict__ kbuf,
    const __hip_bfloat16* __restrict__ vbufT, const float* __restrict__ scores,
    float* __restrict__ out) {
  __shared__ __align__(16) short Ks[3][64 * 72];   // 3 x 9216 B (reduce scratch lo)
  __shared__ __align__(16) short Vs[3][64 * 72];   // 3 x 9216 B (reduce scratch hi)
  __shared__ __align__(16) float Bt[3][192];       // 3 x  768 B  => 57.6 KB total
  const int bh   = blockIdx.x;
  const int b    = bh >> 4, h = bh & 15;
  const int tid  = threadIdx.x;                  // 0..511
  const int lane = tid & 63;
  const int w    = tid >> 6;                     // 0..7
  const int wv   = w & 3;                        // q-row group (rows wv*32..+31)
  const int kw   = w >> 2;                       // key half within each tile
  const int n32  = lane & 31, hf = lane >> 5;
  const int i0b  = blockIdx.y * 128;
  const int i0   = i0b + wv * 32;
  const __hip_bfloat16* qb = qbuf + (size_t)bh * SL * DH;
  const short* kb = (const short*)(kbuf + (size_t)bh * SL * DH);
  const short* vb = (const short*)(vbufT + (size_t)bh * DH * SL);
  const float* sc = scores + h * SCP;

  bf16x8 qf[4];
#pragma unroll
  for (int kc = 0; kc < 4; ++kc)
    qf[kc] = *(const bf16x8*)&qb[(size_t)(i0 + n32) * DH + kc * 16 + hf * 8];

  f32x16 ot[2];    // O^T partial: hd = dt*32 + (r&3)+8*(r>>2)+4*hf, qrow = n32
#pragma unroll
  for (int dt = 0; dt < 2; ++dt)
#pragma unroll
    for (int r = 0; r < 16; ++r) ot[dt][r] = 0.f;
  float ls[4] = {0.f, 0.f, 0.f, 0.f};

  // thread-invariant LDS offsets
  const int kfoff = (kw * 32 + n32) * 72 + hf * 8;   // + kc*16
  const int tb0   = wv * 32 + n32 - kw * 32 - 4 * hf + 63;

  // stage tile at key offset j0 into buffer bsel (K, V, 192-float bias window)
  auto stage = [&](int bsel, int j0) {
    const short* ksrc = kb + (size_t)j0 * DH;
    {                                            // K: 576 chunks over 512 threads
      int c = tid; int r = c / 9, s = c - r * 9;
      GLD(ksrc + (size_t)r * DH + s * 8, &Ks[bsel][c * 8]);
    }
    if (tid < 64) {
      int c = 512 + tid; int r = c / 9, s = c - r * 9;
      GLD(ksrc + (size_t)r * DH + s * 8, &Ks[bsel][c * 8]);
    }
    {                                            // V: 576 chunks
      int c = tid; int r = c / 9, s = c - r * 9;
      GLD(vb + (size_t)r * SL + j0 + s * 8, &Vs[bsel][c * 8]);
    }
    if (tid < 64) {
      int c = 512 + tid; int r = c / 9, s = c - r * 9;
      GLD(vb + (size_t)r * SL + j0 + s * 8, &Vs[bsel][c * 8]);
    }
    if (tid < 48) GLD(sc + (i0b - j0 + 1984) + tid * 4, &Bt[bsel][tid * 4]);
  };

  // preload fragments for a published buffer: kf (4x b128) + bias C-init
  auto loadF = [&](bf16x8 (&kf)[4], f32x16& st, int bsel) {
#pragma unroll
    for (int kc = 0; kc < 4; ++kc)
      kf[kc] = *(const bf16x8*)&Ks[bsel][kfoff + kc * 16];
    const float* Bp = Bt[bsel];
#pragma unroll
    for (int g = 0; g < 4; ++g)
#pragma unroll
      for (int i = 0; i < 4; ++i) st[g * 4 + i] = Bp[tb0 - 8 * g - i];
  };

  // compute tile using preloaded frags; vf read from LDS inside (has slack)
  auto compute = [&](bf16x8 (&kf)[4], f32x16& st, int bsel) {
    const short* Vp = Vs[bsel];
    __builtin_amdgcn_s_setprio(1);
#pragma unroll
    for (int kc = 0; kc < 4; ++kc)
      st = __builtin_amdgcn_mfma_f32_32x32x16_bf16(kf[kc], qf[kc], st, 0, 0, 0);
    __builtin_amdgcn_s_setprio(0);
    // softmax numerator in-place + P-assembly (all-VALU, no LDS):
#pragma unroll
    for (int g = 0; g < 4; ++g)
#pragma unroll
      for (int i = 0; i < 4; ++i) {
        st[g * 4 + i] = fexp2(st[g * 4 + i]);
        ls[g] += st[g * 4 + i];
      }
    uint32_t a0 = cvtpk_bf16(st[0],  st[1]),  a1 = cvtpk_bf16(st[2],  st[3]);
    uint32_t b0 = cvtpk_bf16(st[4],  st[5]),  b1 = cvtpk_bf16(st[6],  st[7]);
    uint32_t c0 = cvtpk_bf16(st[8],  st[9]),  c1 = cvtpk_bf16(st[10], st[11]);
    uint32_t d0 = cvtpk_bf16(st[12], st[13]), d1 = cvtpk_bf16(st[14], st[15]);
    PLSWAP(a0, b0); PLSWAP(a1, b1);            // pf0 = {a0,a1,b0,b1}
    PLSWAP(c0, d0); PLSWAP(c1, d1);            // pf1 = {c0,c1,d0,d1}
    union { uint32_t u[4]; bf16x8 v; } P0, P1;
    P0.u[0] = a0; P0.u[1] = a1; P0.u[2] = b0; P0.u[3] = b1;
    P1.u[0] = c0; P1.u[1] = c1; P1.u[2] = d0; P1.u[3] = d1;
    const bf16x8 pf0 = P0.v, pf1 = P1.v;
    __builtin_amdgcn_s_setprio(1);
#pragma unroll
    for (int dt = 0; dt < 2; ++dt) {
      const short* vr = &Vp[(dt * 32 + n32) * 72 + kw * 32];
      bf16x8 vf0 = *(const bf16x8*)&vr[hf * 8];
      bf16x8 vf1 = *(const bf16x8*)&vr[16 + hf * 8];
      ot[dt] = __builtin_amdgcn_mfma_f32_32x32x16_bf16(vf0, pf0, ot[dt], 0, 0, 0);
      ot[dt] = __builtin_amdgcn_mfma_f32_32x32x16_bf16(vf1, pf1, ot[dt], 0, 0, 0);
    }
    __builtin_amdgcn_s_setprio(0);
  };

  // --- triple-buffered pipeline, 2-tile unroll (ping-pong frag sets A/B) ---
  bf16x8 kfA[4], kfB[4];
  f32x16 stA, stB;
  stage(0, 0);
  stage(1, 64);
  __syncthreads();                 // publish buffers 0 and 1
  loadF(kfA, stA, 0);              // frags for tile 0
  int bcur = 0, bnxt = 1, bfar = 2;
#pragma unroll 1
  for (int t = 0; t < 32; t += 2) {
    // even tile t: compute A, preload B (tile t+1)
    if (t + 2 < 32) stage(bfar, (t + 2) * 64);
    loadF(kfB, stB, bnxt);         // t+1 <= 31 always here
    compute(kfA, stA, bcur);
    __syncthreads();               // publish bfar; all reads of bcur done
    { int tmp = bcur; bcur = bnxt; bnxt = bfar; bfar = tmp; }
    // odd tile t+1: compute B, preload A (tile t+2)
    if (t + 3 < 32) stage(bfar, (t + 3) * 64);
    if (t + 2 < 32) loadF(kfA, stA, bnxt);
    compute(kfB, stB, bcur);
    __syncthreads();               // publish bfar; safe scratch reuse after loop
    { int tmp = bcur; bcur = bnxt; bnxt = bfar; bfar = tmp; }
  }

  // ---- cross-wave reduce: kw=1 waves dump partials; slot = (wv,lane) ----
  float lsum = (ls[0] + ls[1]) + (ls[2] + ls[3]);
  lsum += __shfl_xor(lsum, 32);
  // 256 slots x 36 floats (144B): wv 0,1 -> Ks area, wv 2,3 -> Vs area.
  float* red = (wv < 2)
      ? (float*)&Ks[0][0] + ((wv * 64 + lane) * 36)
      : (float*)&Vs[0][0] + (((wv - 2) * 64 + lane) * 36);
  if (kw == 1) {
#pragma unroll
    for (int dt = 0; dt < 2; ++dt)
#pragma unroll
      for (int g = 0; g < 4; ++g) {
        f32x4 v;
#pragma unroll
        for (int i = 0; i < 4; ++i) v[i] = ot[dt][g * 4 + i];
        *(f32x4*)&red[dt * 16 + g * 4] = v;
      }
    red[32] = lsum;
  }
  __syncthreads();
  if (kw == 0) {
#pragma unroll
    for (int dt = 0; dt < 2; ++dt)
#pragma unroll
      for (int g = 0; g < 4; ++g) {
        f32x4 v = *(const f32x4*)&red[dt * 16 + g * 4];
#pragma unroll
        for (int i = 0; i < 4; ++i) ot[dt][g * 4 + i] += v[i];
      }
    lsum += red[32];
    const float inv = 1.f / lsum;
    float* orow = out + (((size_t)b * SL + i0 + n32) * NH + h) * DH;
#pragma unroll
    for (int dt = 0; dt < 2; ++dt)
#pragma unroll
      for (int g = 0; g < 4; ++g) {
        f32x4 v;
#pragma unroll
        for (int i = 0; i < 4; ++i) v[i] = ot[dt][g * 4 + i] * inv;
        *(f32x4*)&orow[dt * 32 + 8 * g + 4 * hf] = v;
      }
  }
}

// ---------------------------------------------------------------- launch
extern "C" void kernel_launch(void* const* d_in, const int* in_sizes, int n_in,
                              void* d_out, int out_size, void* d_ws, size_t ws_size,
                              hipStream_t stream) {
  const float* x    = (const float*)d_in[0];   // (B,L,D) fp32
  const float* w    = (const float*)d_in[1];   // (3D,D) fp32
  const float* koff = (const float*)d_in[2];   // (H,K) fp32
  const float* kamp = (const float*)d_in[3];
  const float* kshp = (const float*)d_in[4];
  float* out = (float*)d_out;                  // (B,L,D) fp32

  const size_t per = (size_t)NB * NH * SL * DH;               // 4,194,304 elems
  const size_t nx  = (size_t)NB * SL * DMODEL;                // 4,194,304
  const size_t nw  = (size_t)3 * DMODEL * DMODEL;             // 3,145,728

  __hip_bfloat16* kbuf  = (__hip_bfloat16*)d_ws;              // 8 MB
  __hip_bfloat16* vbufT = kbuf + per;                         // 8 MB
  __hip_bfloat16* qbuf  = vbufT + per;                        // 8 MB
  float* scores = (float*)(qbuf + per);                       // 256 KB
  short* xbf    = (short*)(scores + (size_t)NH * SCP);        // 8 MB
  short* wbf    = xbf + nx;                                   // 6 MB   => ~38.3 MB total

  prep_k<<<3840, 256, 0, stream>>>(x, w, koff, kamp, kshp, xbf, wbf, scores);
  qkv_gemm_k<<<dim3(48, 32), 256, 0, stream>>>(xbf, wbf, kbuf, vbufT, qbuf);
  attn_k<<<dim3(NB * NH, SL / 128), 512, 0, stream>>>(qbuf, kbuf, vbufT, scores, out);
}

// Round 10
// 173.363 us; speedup vs baseline: 1.4303x; 1.4303x over previous
//
#include <hip/hip_runtime.h>
#include <hip/hip_bf16.h>
#include <stdint.h>
#include <stddef.h>

// Problem: B=2, L=2048, D=1024, H=16, HD=64.
// Inputs FP32, output FP32.  Internal pipeline bf16 MFMA.
// R22: (a) R21's triple-buffer REVERTED (aggregate ping-pong spilled to
// scratch: 295MB WRITE_SIZE, 135us).  Back to R20 double-buffer structure.
// (b) attn is LDS-PIPE-BOUND (per-wave-tile: bias 16xb32=93cy + kf/vf
// 8xb128=96cy; x16 waves x32 tiles x2 blocks ~= 40us of the 55us).  The
// bias C-init (half the LDS load) moves OFF the LDS pipe: 16 direct
// global_load_dword from the L2-resident score row (VMEM pipe, idle),
// issued at compute top; QK runs with C=0, bias added post-MFMA (16 v_add,
// ~200cy slack covers L2 latency).  Bias leaves stage() and LDS entirely.
// R20: cvt_pk_bf16 + permlane32_swap P-assembly (54.8us best).
// R17: 512-thread / 8-wave blocks, Q-tile 128 rows per staged K/V tile.
// R14: kw key-split + LDS reduce; gemm 128x64 BK=64 (best measured).
// R13: prefetch pipeline, one barrier/tile, exp2 with folded log2e.

#define NB     2
#define NH     16
#define SL     2048
#define DH     64
#define DMODEL 1024
#define SCP    4096   // padded scores row stride (floats); 4095 real
#define LOG2E  1.44269504088896340736f

typedef __attribute__((ext_vector_type(8)))  short bf16x8;
typedef __attribute__((ext_vector_type(4)))  short bf16x4;
typedef __attribute__((ext_vector_type(4)))  float f32x4;
typedef __attribute__((ext_vector_type(16))) float f32x16;

static __device__ __forceinline__ short f2bf(float x) {   // RNE
  __hip_bfloat16 h = __float2bfloat16(x);
  return *reinterpret_cast<short*>(&h);
}
static __device__ __forceinline__ short f2bf_fast(float x) {  // round-half-up
  union { float f; uint32_t u; } v; v.f = x;
  return (short)((v.u + 0x8000u) >> 16);
}
static __device__ __forceinline__ float fexp2(float x) {
#if __has_builtin(__builtin_amdgcn_exp2f)
  return __builtin_amdgcn_exp2f(x);
#else
  return __expf(x * 0.69314718056f);
#endif
}
static __device__ __forceinline__ uint32_t cvtpk_bf16(float lo, float hi) {
  uint32_t r;
  asm("v_cvt_pk_bf16_f32 %0, %1, %2" : "=v"(r) : "v"(lo), "v"(hi));
  return r;
}
// swaps a's upper-32 lanes with b's lower-32 lanes (CDNA4)
#define PLSWAP(a, b) asm("v_permlane32_swap_b32 %0, %1" : "+v"(a), "+v"(b))

#define GLD(g, l) __builtin_amdgcn_global_load_lds( \
    (const __attribute__((address_space(1))) void*)(g), \
    (__attribute__((address_space(3))) void*)(l), 16, 0, 0)

// ---------------------------------------------------- prep: cvt x, cvt w, bias
__global__ __launch_bounds__(256) void prep_k(
    const float* __restrict__ x, const float* __restrict__ w,
    const float* __restrict__ koff, const float* __restrict__ kamp,
    const float* __restrict__ kshp,
    short* __restrict__ xbf, short* __restrict__ wbf,
    float* __restrict__ scores) {
  const int bx = blockIdx.x, tid = threadIdx.x;
  if (bx < 3584) {
    const float* src = (bx < 2048) ? x : w;
    short* dst       = (bx < 2048) ? xbf : wbf;
    const size_t i   = ((size_t)(bx < 2048 ? bx : bx - 2048) * 256 + tid) * 8;
    float4 a = *(const float4*)(src + i);
    float4 b = *(const float4*)(src + i + 4);
    bf16x8 o;
    o[0] = f2bf(a.x); o[1] = f2bf(a.y); o[2] = f2bf(a.z); o[3] = f2bf(a.w);
    o[4] = f2bf(b.x); o[5] = f2bf(b.y); o[6] = f2bf(b.z); o[7] = f2bf(b.w);
    *(bf16x8*)(dst + i) = o;
  } else {
    const int idx = bx - 3584;
    const int h = idx >> 4;
    const int r = (idx & 15) * 256 + tid;
    if (r >= 4095) return;
    float rel = (float)(r - (SL - 1));
    float acc = 0.f;
#pragma unroll
    for (int k = 0; k < 16; ++k) {
      float o = koff[h * 16 + k];
      float a = kamp[h * 16 + k];
      float s = fabsf(kshp[h * 16 + k]);
      float d = o - rel;
      acc += a * __expf(-s * d * d);
    }
    scores[h * SCP + r] = acc * LOG2E;   // pre-scaled for exp2 in attn
  }
}

// ---------------------------------------------------------------- QKV GEMM
// (verbatim R14/R17 -- best measured config)
__global__ __launch_bounds__(256) void qkv_gemm_k(
    const short* __restrict__ A, const short* __restrict__ Bw,
    __hip_bfloat16* __restrict__ kbuf, __hip_bfloat16* __restrict__ vbufT,
    __hip_bfloat16* __restrict__ qbuf) {
  __shared__ __align__(16) short SM[12288];       // 24 KB; As | Bs, reused by epilogue
  short* As = SM;                                  // 128*64 shorts
  short* Bs = SM + 8192;                           // 64*64 shorts
  const int tid  = threadIdx.x;
  const int lane = tid & 63;
  const int wv   = tid >> 6;
  const int l15  = lane & 15, quad = lane >> 4;
  const int wm = (wv & 1) * 64, wn = (wv >> 1) * 32;
  const int xt = blockIdx.x, yt = blockIdx.y;
  const int m0 = yt * 128, n0 = xt * 64;
  const int which = xt >> 4;                       // 0=k, 1=v, 2=q
  const int hh    = xt & 15;                       // the head this tile serves

  f32x4 acc[4][2];
#pragma unroll
  for (int r = 0; r < 4; ++r)
#pragma unroll
    for (int c = 0; c < 2; ++c) acc[r][c] = (f32x4){0.f, 0.f, 0.f, 0.f};

  for (int kt = 0; kt < 16; ++kt) {
    const int k0 = kt * 64;
#pragma unroll
    for (int it = 0; it < 4; ++it) {               // A: 1024 chunks
      const int e8  = it * 256 + tid;
      GLD(A + (size_t)(m0 + (e8 >> 3)) * DMODEL + k0 + (e8 & 7) * 8, &As[e8 * 8]);
    }
#pragma unroll
    for (int it = 0; it < 2; ++it) {               // B: 512 chunks
      const int e8  = it * 256 + tid;
      GLD(Bw + (size_t)(n0 + (e8 >> 3)) * DMODEL + k0 + (e8 & 7) * 8, &Bs[e8 * 8]);
    }
    __syncthreads();
#pragma unroll
    for (int ki = 0; ki < 64; ki += 32) {
      bf16x8 af[4], bfv[2];
#pragma unroll
      for (int r = 0; r < 4; ++r)
        af[r] = *(const bf16x8*)&As[(wm + r * 16 + l15) * 64 + ki + quad * 8];
#pragma unroll
      for (int c = 0; c < 2; ++c)
        bfv[c] = *(const bf16x8*)&Bs[(wn + c * 16 + l15) * 64 + ki + quad * 8];
#pragma unroll
      for (int r = 0; r < 4; ++r)
#pragma unroll
        for (int c = 0; c < 2; ++c)
          acc[r][c] = __builtin_amdgcn_mfma_f32_16x16x32_bf16(af[r], bfv[c], acc[r][c], 0, 0, 0);
    }
    __syncthreads();
  }

  // ---- epilogue: C/D layout m = wm+r*16+quad*4+g, n = wn+c*16+l15 ----
  const int bb  = m0 >> 11;
  const int llb = m0 & 2047;
  if (which != 1) {
    const float qs = (which == 2) ? 0.125f * LOG2E : 1.0f;  // log2e folded into q
#pragma unroll
    for (int r = 0; r < 4; ++r)
#pragma unroll
      for (int c = 0; c < 2; ++c)
#pragma unroll
        for (int gg = 0; gg < 4; ++gg)
          SM[(wm + r * 16 + quad * 4 + gg) * 72 + wn + c * 16 + l15] =
              f2bf_fast(acc[r][c][gg] * qs);
    __syncthreads();
    __hip_bfloat16* dst = (which == 0) ? kbuf : qbuf;
#pragma unroll
    for (int i = 0; i < 4; ++i) {
      const int cidx = i * 256 + tid;              // 1024 16B chunks
      const int m = cidx >> 3, ch = cidx & 7;
      bf16x8 val = *(const bf16x8*)&SM[m * 72 + ch * 8];
      *(bf16x8*)&dst[(((size_t)bb * NH + hh) * SL + llb + m) * DH + ch * 8] = val;
    }
  } else {
#pragma unroll
    for (int r = 0; r < 4; ++r)
#pragma unroll
      for (int c = 0; c < 2; ++c) {
        bf16x4 pk;
#pragma unroll
        for (int gg = 0; gg < 4; ++gg) pk[gg] = f2bf_fast(acc[r][c][gg]);
        *(bf16x4*)&SM[(wn + c * 16 + l15) * 136 + wm + r * 16 + quad * 4] = pk;
      }
    __syncthreads();
#pragma unroll
    for (int i = 0; i < 4; ++i) {
      const int cidx = i * 256 + tid;              // 1024 16B chunks
      const int n = cidx >> 4, ch = cidx & 15;
      bf16x8 val = *(const bf16x8*)&SM[n * 136 + ch * 8];
      *(bf16x8*)&vbufT[(((size_t)bb * NH + hh) * DH + n) * SL + llb + ch * 8] = val;
    }
  }
}

// ---------------------------------------------------------------- attention
// R22: bias via direct global loads (VMEM pipe) + post-QK v_add; K/V double-
// buffered in LDS (R20 structure).  P-assembly: cvt_pk + permlane32_swap.
// LDS: Ks 2x9216 + Vs 2x9216 = 36864 B; 2 blocks/CU x 8 waves.
__global__ __launch_bounds__(512, 4) void attn_k(
    const __hip_bfloat16* __restrict__ qbuf, const __hip_bfloat16* __restrict__ kbuf,
    const __hip_bfloat16* __restrict__ vbufT, const float* __restrict__ scores,
    float* __restrict__ out) {
  __shared__ __align__(16) short Ks[2][64 * 72];   // 2 x 9216 B (reduce scratch lo)
  __shared__ __align__(16) short Vs[2][64 * 72];   // 2 x 9216 B (reduce scratch hi)
  const int bh   = blockIdx.x;
  const int b    = bh >> 4, h = bh & 15;
  const int tid  = threadIdx.x;                  // 0..511
  const int lane = tid & 63;
  const int w    = tid >> 6;                     // 0..7
  const int wv   = w & 3;                        // q-row group (rows wv*32..+31)
  const int kw   = w >> 2;                       // key half within each tile
  const int n32  = lane & 31, hf = lane >> 5;
  const int i0b  = blockIdx.y * 128;
  const int i0   = i0b + wv * 32;
  const __hip_bfloat16* qb = qbuf + (size_t)bh * SL * DH;
  const short* kb = (const short*)(kbuf + (size_t)bh * SL * DH);
  const short* vb = (const short*)(vbufT + (size_t)bh * DH * SL);
  const float* sc = scores + h * SCP;
  // per-lane global bias base: bias[st row g*4+i, tile j0] = gbase[-j0 -8g -i]
  const float* gbase = sc + (i0 + n32 - kw * 32 - 4 * hf + 2047);

  bf16x8 qf[4];
#pragma unroll
  for (int kc = 0; kc < 4; ++kc)
    qf[kc] = *(const bf16x8*)&qb[(size_t)(i0 + n32) * DH + kc * 16 + hf * 8];

  f32x16 ot[2];    // O^T partial: hd = dt*32 + (r&3)+8*(r>>2)+4*hf, qrow = n32
#pragma unroll
  for (int dt = 0; dt < 2; ++dt)
#pragma unroll
    for (int r = 0; r < 16; ++r) ot[dt][r] = 0.f;
  float ls[4] = {0.f, 0.f, 0.f, 0.f};

  // stage tile at key offset j0 into buffer bsel (K and V only)
  auto stage = [&](int bsel, int j0) {
    const short* ksrc = kb + (size_t)j0 * DH;
    {                                            // K: 576 chunks over 512 threads
      int c = tid; int r = c / 9, s = c - r * 9;
      GLD(ksrc + (size_t)r * DH + s * 8, &Ks[bsel][c * 8]);
    }
    if (tid < 64) {
      int c = 512 + tid; int r = c / 9, s = c - r * 9;
      GLD(ksrc + (size_t)r * DH + s * 8, &Ks[bsel][c * 8]);
    }
    {                                            // V: 576 chunks
      int c = tid; int r = c / 9, s = c - r * 9;
      GLD(vb + (size_t)r * SL + j0 + s * 8, &Vs[bsel][c * 8]);
    }
    if (tid < 64) {
      int c = 512 + tid; int r = c / 9, s = c - r * 9;
      GLD(vb + (size_t)r * SL + j0 + s * 8, &Vs[bsel][c * 8]);
    }
  };

  auto compute = [&](int bsel, int j0) {
    const short* Kp = Ks[bsel];
    const short* Vp = Vs[bsel];
    // bias direct from global (L2-resident score row, VMEM pipe): issue
    // first so the 4 QK MFMAs below cover the ~200cy L2 latency.
    const float* gb = gbase - j0;
    float bb[16];
#pragma unroll
    for (int g = 0; g < 4; ++g)
#pragma unroll
      for (int i = 0; i < 4; ++i) bb[g * 4 + i] = gb[-8 * g - i];
    f32x16 st;
#pragma unroll
    for (int r = 0; r < 16; ++r) st[r] = 0.f;
    __builtin_amdgcn_s_setprio(1);
#pragma unroll
    for (int kc = 0; kc < 4; ++kc) {
      bf16x8 kf = *(const bf16x8*)&Kp[(kw * 32 + n32) * 72 + kc * 16 + hf * 8];
      st = __builtin_amdgcn_mfma_f32_32x32x16_bf16(kf, qf[kc], st, 0, 0, 0);
    }
    __builtin_amdgcn_s_setprio(0);
    // softmax numerator (bias added post-MFMA) + P-assembly (no LDS):
#pragma unroll
    for (int g = 0; g < 4; ++g)
#pragma unroll
      for (int i = 0; i < 4; ++i) {
        st[g * 4 + i] = fexp2(st[g * 4 + i] + bb[g * 4 + i]);
        ls[g] += st[g * 4 + i];
      }
    uint32_t a0 = cvtpk_bf16(st[0],  st[1]),  a1 = cvtpk_bf16(st[2],  st[3]);
    uint32_t b0 = cvtpk_bf16(st[4],  st[5]),  b1 = cvtpk_bf16(st[6],  st[7]);
    uint32_t c0 = cvtpk_bf16(st[8],  st[9]),  c1 = cvtpk_bf16(st[10], st[11]);
    uint32_t d0 = cvtpk_bf16(st[12], st[13]), d1 = cvtpk_bf16(st[14], st[15]);
    PLSWAP(a0, b0); PLSWAP(a1, b1);            // pf0 = {a0,a1,b0,b1}
    PLSWAP(c0, d0); PLSWAP(c1, d1);            // pf1 = {c0,c1,d0,d1}
    union { uint32_t u[4]; bf16x8 v; } P0, P1;
    P0.u[0] = a0; P0.u[1] = a1; P0.u[2] = b0; P0.u[3] = b1;
    P1.u[0] = c0; P1.u[1] = c1; P1.u[2] = d0; P1.u[3] = d1;
    const bf16x8 pf0 = P0.v, pf1 = P1.v;
    __builtin_amdgcn_s_setprio(1);
#pragma unroll
    for (int dt = 0; dt < 2; ++dt) {
      const short* vr = &Vp[(dt * 32 + n32) * 72 + kw * 32];
      bf16x8 vf0 = *(const bf16x8*)&vr[hf * 8];
      bf16x8 vf1 = *(const bf16x8*)&vr[16 + hf * 8];
      ot[dt] = __builtin_amdgcn_mfma_f32_32x32x16_bf16(vf0, pf0, ot[dt], 0, 0, 0);
      ot[dt] = __builtin_amdgcn_mfma_f32_32x32x16_bf16(vf1, pf1, ot[dt], 0, 0, 0);
    }
    __builtin_amdgcn_s_setprio(0);
  };

  // software pipeline: stage(t+1) issued BEFORE compute(t); one barrier/tile.
  stage(0, 0);
  __syncthreads();                 // drains prologue GLDs
  int cur = 0;
  for (int j0 = 64; j0 < SL; j0 += 64) {
    stage(cur ^ 1, j0);            // prefetch next tile (lands during compute)
    compute(cur, j0 - 64);
    __syncthreads();               // vmcnt(0)+barrier: prefetch complete, reads done
    cur ^= 1;
  }
  compute(cur, SL - 64);           // last tile, no prefetch
  __syncthreads();                 // all waves done with Ks/Vs before scratch reuse

  // ---- cross-wave reduce: kw=1 waves dump partials; slot = (wv,lane) ----
  float lsum = (ls[0] + ls[1]) + (ls[2] + ls[3]);
  lsum += __shfl_xor(lsum, 32);
  // 256 slots x 36 floats (144B): wv 0,1 -> Ks area, wv 2,3 -> Vs area.
  float* red = (wv < 2)
      ? (float*)&Ks[0][0] + ((wv * 64 + lane) * 36)
      : (float*)&Vs[0][0] + (((wv - 2) * 64 + lane) * 36);
  if (kw == 1) {
#pragma unroll
    for (int dt = 0; dt < 2; ++dt)
#pragma unroll
      for (int g = 0; g < 4; ++g) {
        f32x4 v;
#pragma unroll
        for (int i = 0; i < 4; ++i) v[i] = ot[dt][g * 4 + i];
        *(f32x4*)&red[dt * 16 + g * 4] = v;
      }
    red[32] = lsum;
  }
  __syncthreads();
  if (kw == 0) {
#pragma unroll
    for (int dt = 0; dt < 2; ++dt)
#pragma unroll
      for (int g = 0; g < 4; ++g) {
        f32x4 v = *(const f32x4*)&red[dt * 16 + g * 4];
#pragma unroll
        for (int i = 0; i < 4; ++i) ot[dt][g * 4 + i] += v[i];
      }
    lsum += red[32];
    const float inv = 1.f / lsum;
    float* orow = out + (((size_t)b * SL + i0 + n32) * NH + h) * DH;
#pragma unroll
    for (int dt = 0; dt < 2; ++dt)
#pragma unroll
      for (int g = 0; g < 4; ++g) {
        f32x4 v;
#pragma unroll
        for (int i = 0; i < 4; ++i) v[i] = ot[dt][g * 4 + i] * inv;
        *(f32x4*)&orow[dt * 32 + 8 * g + 4 * hf] = v;
      }
  }
}

// ---------------------------------------------------------------- launch
extern "C" void kernel_launch(void* const* d_in, const int* in_sizes, int n_in,
                              void* d_out, int out_size, void* d_ws, size_t ws_size,
                              hipStream_t stream) {
  const float* x    = (const float*)d_in[0];   // (B,L,D) fp32
  const float* w    = (const float*)d_in[1];   // (3D,D) fp32
  const float* koff = (const float*)d_in[2];   // (H,K) fp32
  const float* kamp = (const float*)d_in[3];
  const float* kshp = (const float*)d_in[4];
  float* out = (float*)d_out;                  // (B,L,D) fp32

  const size_t per = (size_t)NB * NH * SL * DH;               // 4,194,304 elems
  const size_t nx  = (size_t)NB * SL * DMODEL;                // 4,194,304
  const size_t nw  = (size_t)3 * DMODEL * DMODEL;             // 3,145,728

  __hip_bfloat16* kbuf  = (__hip_bfloat16*)d_ws;              // 8 MB
  __hip_bfloat16* vbufT = kbuf + per;                         // 8 MB
  __hip_bfloat16* qbuf  = vbufT + per;                        // 8 MB
  float* scores = (float*)(qbuf + per);                       // 256 KB
  short* xbf    = (short*)(scores + (size_t)NH * SCP);        // 8 MB
  short* wbf    = xbf + nx;                                   // 6 MB   => ~38.3 MB total

  prep_k<<<3840, 256, 0, stream>>>(x, w, koff, kamp, kshp, xbf, wbf, scores);
  qkv_gemm_k<<<dim3(48, 32), 256, 0, stream>>>(xbf, wbf, kbuf, vbufT, qbuf);
  attn_k<<<dim3(NB * NH, SL / 128), 512, 0, stream>>>(qbuf, kbuf, vbufT, scores, out);
}

// Round 11
// 168.825 us; speedup vs baseline: 1.4688x; 1.0269x over previous
//
#include <hip/hip_runtime.h>
#include <hip/hip_bf16.h>
#include <stdint.h>
#include <stddef.h>

// Problem: B=2, L=2048, D=1024, H=16, HD=64.
// Inputs FP32, output FP32.  Internal pipeline bf16 MFMA.
// R23: RESTORE R20 exactly -- the best measured config (170.3us total,
// attn 54.8us).  Post-R20 experiments all regressed and are reverted:
//   R21 triple-buffer+frag-preload: aggregate ping-pong spilled to scratch
//       (WRITE_SIZE 16MB->295MB, 135us).
//   R22 bias-from-global: 16 VMEM scalar loads/tile cost more than the
//       conflict-free LDS reads they replaced (59.0us).
//   R19 rotated-bias-copies: 6.3M bank conflicts (67.8us).
// attn structure: 512-thread/8-wave blocks, Q-tile 128 rows, kw key-split,
// double-buffered K/V/bias LDS staging (stage-ahead, one barrier/tile),
// bias as MFMA C-init via scalar stride-1 LDS reads (conflict-free),
// P-assembly via v_cvt_pk_bf16_f32 + v_permlane32_swap_b32 (no LDS, no
// divergent selects), exp2 with log2e folded into q-scale and bias table,
// cross-wave LDS reduce.  gemm: 128x64 BK=64 2-barrier loop (R15/R18
// restructures both regressed).  prep: 8 elems/thread convert + bias table.

#define NB     2
#define NH     16
#define SL     2048
#define DH     64
#define DMODEL 1024
#define SCP    4096   // padded scores row stride (floats); 4095 real
#define LOG2E  1.44269504088896340736f

typedef __attribute__((ext_vector_type(8)))  short bf16x8;
typedef __attribute__((ext_vector_type(4)))  short bf16x4;
typedef __attribute__((ext_vector_type(4)))  float f32x4;
typedef __attribute__((ext_vector_type(16))) float f32x16;

static __device__ __forceinline__ short f2bf(float x) {   // RNE
  __hip_bfloat16 h = __float2bfloat16(x);
  return *reinterpret_cast<short*>(&h);
}
static __device__ __forceinline__ short f2bf_fast(float x) {  // round-half-up
  union { float f; uint32_t u; } v; v.f = x;
  return (short)((v.u + 0x8000u) >> 16);
}
static __device__ __forceinline__ float fexp2(float x) {
#if __has_builtin(__builtin_amdgcn_exp2f)
  return __builtin_amdgcn_exp2f(x);
#else
  return __expf(x * 0.69314718056f);
#endif
}
static __device__ __forceinline__ uint32_t cvtpk_bf16(float lo, float hi) {
  uint32_t r;
  asm("v_cvt_pk_bf16_f32 %0, %1, %2" : "=v"(r) : "v"(lo), "v"(hi));
  return r;
}
// swaps a's upper-32 lanes with b's lower-32 lanes (CDNA4)
#define PLSWAP(a, b) asm("v_permlane32_swap_b32 %0, %1" : "+v"(a), "+v"(b))

#define GLD(g, l) __builtin_amdgcn_global_load_lds( \
    (const __attribute__((address_space(1))) void*)(g), \
    (__attribute__((address_space(3))) void*)(l), 16, 0, 0)

// ---------------------------------------------------- prep: cvt x, cvt w, bias
// blocks: [0,2048) x-convert, [2048,3584) w-convert, [3584,3840) bias.
// 8 elems/thread (2x float4 -> bf16x8).
__global__ __launch_bounds__(256) void prep_k(
    const float* __restrict__ x, const float* __restrict__ w,
    const float* __restrict__ koff, const float* __restrict__ kamp,
    const float* __restrict__ kshp,
    short* __restrict__ xbf, short* __restrict__ wbf,
    float* __restrict__ scores) {
  const int bx = blockIdx.x, tid = threadIdx.x;
  if (bx < 3584) {
    const float* src = (bx < 2048) ? x : w;
    short* dst       = (bx < 2048) ? xbf : wbf;
    const size_t i   = ((size_t)(bx < 2048 ? bx : bx - 2048) * 256 + tid) * 8;
    float4 a = *(const float4*)(src + i);
    float4 b = *(const float4*)(src + i + 4);
    bf16x8 o;
    o[0] = f2bf(a.x); o[1] = f2bf(a.y); o[2] = f2bf(a.z); o[3] = f2bf(a.w);
    o[4] = f2bf(b.x); o[5] = f2bf(b.y); o[6] = f2bf(b.z); o[7] = f2bf(b.w);
    *(bf16x8*)(dst + i) = o;
  } else {
    const int idx = bx - 3584;
    const int h = idx >> 4;
    const int r = (idx & 15) * 256 + tid;
    if (r >= 4095) return;
    float rel = (float)(r - (SL - 1));
    float acc = 0.f;
#pragma unroll
    for (int k = 0; k < 16; ++k) {
      float o = koff[h * 16 + k];
      float a = kamp[h * 16 + k];
      float s = fabsf(kshp[h * 16 + k]);
      float d = o - rel;
      acc += a * __expf(-s * d * d);
    }
    scores[h * SCP + r] = acc * LOG2E;   // pre-scaled for exp2 in attn
  }
}

// ---------------------------------------------------------------- QKV GEMM
// (verbatim R14/R17 -- best measured config)
// C[m,n] = sum_k x[m,k] * w_in[n,k].  Tile 128x64, BK=64, 16 steps.
// Grid (48 n-tiles, 32 m-tiles) = 1536 blocks = 6/CU (LDS 24KB).
// Each n-tile = one head's 64 cols; slot = xt>>4 (0=k,1=v,2=q).
__global__ __launch_bounds__(256) void qkv_gemm_k(
    const short* __restrict__ A, const short* __restrict__ Bw,
    __hip_bfloat16* __restrict__ kbuf, __hip_bfloat16* __restrict__ vbufT,
    __hip_bfloat16* __restrict__ qbuf) {
  __shared__ __align__(16) short SM[12288];       // 24 KB; As | Bs, reused by epilogue
  short* As = SM;                                  // 128*64 shorts
  short* Bs = SM + 8192;                           // 64*64 shorts
  const int tid  = threadIdx.x;
  const int lane = tid & 63;
  const int wv   = tid >> 6;
  const int l15  = lane & 15, quad = lane >> 4;
  const int wm = (wv & 1) * 64, wn = (wv >> 1) * 32;
  const int xt = blockIdx.x, yt = blockIdx.y;
  const int m0 = yt * 128, n0 = xt * 64;
  const int which = xt >> 4;                       // 0=k, 1=v, 2=q
  const int hh    = xt & 15;                       // the head this tile serves

  f32x4 acc[4][2];
#pragma unroll
  for (int r = 0; r < 4; ++r)
#pragma unroll
    for (int c = 0; c < 2; ++c) acc[r][c] = (f32x4){0.f, 0.f, 0.f, 0.f};

  for (int kt = 0; kt < 16; ++kt) {
    const int k0 = kt * 64;
#pragma unroll
    for (int it = 0; it < 4; ++it) {               // A: 1024 chunks
      const int e8  = it * 256 + tid;
      GLD(A + (size_t)(m0 + (e8 >> 3)) * DMODEL + k0 + (e8 & 7) * 8, &As[e8 * 8]);
    }
#pragma unroll
    for (int it = 0; it < 2; ++it) {               // B: 512 chunks
      const int e8  = it * 256 + tid;
      GLD(Bw + (size_t)(n0 + (e8 >> 3)) * DMODEL + k0 + (e8 & 7) * 8, &Bs[e8 * 8]);
    }
    __syncthreads();
#pragma unroll
    for (int ki = 0; ki < 64; ki += 32) {
      bf16x8 af[4], bfv[2];
#pragma unroll
      for (int r = 0; r < 4; ++r)
        af[r] = *(const bf16x8*)&As[(wm + r * 16 + l15) * 64 + ki + quad * 8];
#pragma unroll
      for (int c = 0; c < 2; ++c)
        bfv[c] = *(const bf16x8*)&Bs[(wn + c * 16 + l15) * 64 + ki + quad * 8];
#pragma unroll
      for (int r = 0; r < 4; ++r)
#pragma unroll
        for (int c = 0; c < 2; ++c)
          acc[r][c] = __builtin_amdgcn_mfma_f32_16x16x32_bf16(af[r], bfv[c], acc[r][c], 0, 0, 0);
    }
    __syncthreads();
  }

  // ---- epilogue: C/D layout m = wm+r*16+quad*4+g, n = wn+c*16+l15 ----
  const int bb  = m0 >> 11;
  const int llb = m0 & 2047;
  if (which != 1) {
    // k/q: LDS [m][n] stride 72 -> b128 row reads -> 16B coalesced stores
    const float qs = (which == 2) ? 0.125f * LOG2E : 1.0f;  // log2e folded into q
#pragma unroll
    for (int r = 0; r < 4; ++r)
#pragma unroll
      for (int c = 0; c < 2; ++c)
#pragma unroll
        for (int gg = 0; gg < 4; ++gg)
          SM[(wm + r * 16 + quad * 4 + gg) * 72 + wn + c * 16 + l15] =
              f2bf_fast(acc[r][c][gg] * qs);
    __syncthreads();
    __hip_bfloat16* dst = (which == 0) ? kbuf : qbuf;
#pragma unroll
    for (int i = 0; i < 4; ++i) {
      const int cidx = i * 256 + tid;              // 1024 16B chunks
      const int m = cidx >> 3, ch = cidx & 7;
      bf16x8 val = *(const bf16x8*)&SM[m * 72 + ch * 8];
      *(bf16x8*)&dst[(((size_t)bb * NH + hh) * SL + llb + m) * DH + ch * 8] = val;
    }
  } else {
    // v: LDS [n][m] stride 136 -> b128 row reads -> [hd][l] 16B stores
#pragma unroll
    for (int r = 0; r < 4; ++r)
#pragma unroll
      for (int c = 0; c < 2; ++c) {
        bf16x4 pk;
#pragma unroll
        for (int gg = 0; gg < 4; ++gg) pk[gg] = f2bf_fast(acc[r][c][gg]);
        *(bf16x4*)&SM[(wn + c * 16 + l15) * 136 + wm + r * 16 + quad * 4] = pk;
      }
    __syncthreads();
#pragma unroll
    for (int i = 0; i < 4; ++i) {
      const int cidx = i * 256 + tid;              // 1024 16B chunks
      const int n = cidx >> 4, ch = cidx & 15;
      bf16x8 val = *(const bf16x8*)&SM[n * 136 + ch * 8];
      *(bf16x8*)&vbufT[(((size_t)bb * NH + hh) * DH + n) * SL + llb + ch * 8] = val;
    }
  }
}

// ---------------------------------------------------------------- attention
// (verbatim R20 -- best measured: 54.8us)
// P-pack via v_cvt_pk_bf16_f32, P redistribution via permlane32_swap
// (no LDS ops, no divergent selects).  Bias path = R17 scalar (conflict-free).
// 512 threads / 8 waves; Q-tile 128 rows; kw=w>>2 splits the 64-key tile.
// LDS: Ks 2x9216 + Vs 2x9216 + Bt 2x768B = 38.4 KB; 2 blocks/CU x 8 waves.
__global__ __launch_bounds__(512, 4) void attn_k(
    const __hip_bfloat16* __restrict__ qbuf, const __hip_bfloat16* __restrict__ kbuf,
    const __hip_bfloat16* __restrict__ vbufT, const float* __restrict__ scores,
    float* __restrict__ out) {
  __shared__ __align__(16) short Ks[2][64 * 72];   // 2 x 9216 B (reduce scratch lo)
  __shared__ __align__(16) short Vs[2][64 * 72];   // 2 x 9216 B (reduce scratch hi)
  __shared__ __align__(16) float Bt[2][192];       // 2 x  768 B  => 38.4 KB total
  const int bh   = blockIdx.x;
  const int b    = bh >> 4, h = bh & 15;
  const int tid  = threadIdx.x;                  // 0..511
  const int lane = tid & 63;
  const int w    = tid >> 6;                     // 0..7
  const int wv   = w & 3;                        // q-row group (rows wv*32..+31)
  const int kw   = w >> 2;                       // key half within each tile
  const int n32  = lane & 31, hf = lane >> 5;
  const int i0b  = blockIdx.y * 128;
  const int i0   = i0b + wv * 32;
  const __hip_bfloat16* qb = qbuf + (size_t)bh * SL * DH;
  const short* kb = (const short*)(kbuf + (size_t)bh * SL * DH);
  const short* vb = (const short*)(vbufT + (size_t)bh * DH * SL);
  const float* sc = scores + h * SCP;

  bf16x8 qf[4];
#pragma unroll
  for (int kc = 0; kc < 4; ++kc)
    qf[kc] = *(const bf16x8*)&qb[(size_t)(i0 + n32) * DH + kc * 16 + hf * 8];

  f32x16 ot[2];    // O^T partial: hd = dt*32 + (r&3)+8*(r>>2)+4*hf, qrow = n32
#pragma unroll
  for (int dt = 0; dt < 2; ++dt)
#pragma unroll
    for (int r = 0; r < 16; ++r) ot[dt][r] = 0.f;
  float ls[4] = {0.f, 0.f, 0.f, 0.f};

  // stage tile at key offset j0 into buffer bsel (K, V, 192-float bias window)
  auto stage = [&](int bsel, int j0) {
    const short* ksrc = kb + (size_t)j0 * DH;
    {                                            // K: 576 chunks over 512 threads
      int c = tid; int r = c / 9, s = c - r * 9;
      GLD(ksrc + (size_t)r * DH + s * 8, &Ks[bsel][c * 8]);
    }
    if (tid < 64) {
      int c = 512 + tid; int r = c / 9, s = c - r * 9;
      GLD(ksrc + (size_t)r * DH + s * 8, &Ks[bsel][c * 8]);
    }
    {                                            // V: 576 chunks
      int c = tid; int r = c / 9, s = c - r * 9;
      GLD(vb + (size_t)r * SL + j0 + s * 8, &Vs[bsel][c * 8]);
    }
    if (tid < 64) {
      int c = 512 + tid; int r = c / 9, s = c - r * 9;
      GLD(vb + (size_t)r * SL + j0 + s * 8, &Vs[bsel][c * 8]);
    }
    // bias window: global idx (i-j)+2047, i_loc in [0,128), j_loc in [0,64)
    // -> spans [i0b-j0+1984, i0b-j0+2174]; 192 floats = 48 chunks
    if (tid < 48) GLD(sc + (i0b - j0 + 1984) + tid * 4, &Bt[bsel][tid * 4]);
  };

  auto compute = [&](int bsel) {
    const short* Kp = Ks[bsel];
    const short* Vp = Vs[bsel];
    const float* Bp = Bt[bsel];
    // bias preloaded as MFMA C operand: local idx (i_loc - j_loc) + 63
    // (scalar stride-1 reads: lanes hit consecutive floats, conflict-free)
    f32x16 st;
    const int tb0 = wv * 32 + n32 - kw * 32 - 4 * hf + 63;
#pragma unroll
    for (int g = 0; g < 4; ++g)
#pragma unroll
      for (int i = 0; i < 4; ++i) st[g * 4 + i] = Bp[tb0 - 8 * g - i];
    __builtin_amdgcn_s_setprio(1);
#pragma unroll
    for (int kc = 0; kc < 4; ++kc) {
      bf16x8 kf = *(const bf16x8*)&Kp[(kw * 32 + n32) * 72 + kc * 16 + hf * 8];
      st = __builtin_amdgcn_mfma_f32_32x32x16_bf16(kf, qf[kc], st, 0, 0, 0);
    }
    __builtin_amdgcn_s_setprio(0);
    // softmax numerator + P-fragment assembly (all-VALU, no LDS):
    float pv[16];
#pragma unroll
    for (int g = 0; g < 4; ++g)
#pragma unroll
      for (int i = 0; i < 4; ++i) {
        pv[g * 4 + i] = fexp2(st[g * 4 + i]);
        ls[g] += pv[g * 4 + i];
      }
    uint32_t a0 = cvtpk_bf16(pv[0],  pv[1]),  a1 = cvtpk_bf16(pv[2],  pv[3]);
    uint32_t b0 = cvtpk_bf16(pv[4],  pv[5]),  b1 = cvtpk_bf16(pv[6],  pv[7]);
    uint32_t c0 = cvtpk_bf16(pv[8],  pv[9]),  c1 = cvtpk_bf16(pv[10], pv[11]);
    uint32_t d0 = cvtpk_bf16(pv[12], pv[13]), d1 = cvtpk_bf16(pv[14], pv[15]);
    PLSWAP(a0, b0); PLSWAP(a1, b1);            // pf0 = {a0,a1,b0,b1}
    PLSWAP(c0, d0); PLSWAP(c1, d1);            // pf1 = {c0,c1,d0,d1}
    union { uint32_t u[4]; bf16x8 v; } P0, P1;
    P0.u[0] = a0; P0.u[1] = a1; P0.u[2] = b0; P0.u[3] = b1;
    P1.u[0] = c0; P1.u[1] = c1; P1.u[2] = d0; P1.u[3] = d1;
    const bf16x8 pf0 = P0.v, pf1 = P1.v;
    __builtin_amdgcn_s_setprio(1);
#pragma unroll
    for (int dt = 0; dt < 2; ++dt) {
      const short* vr = &Vp[(dt * 32 + n32) * 72 + kw * 32];
      bf16x8 vf0 = *(const bf16x8*)&vr[hf * 8];
      bf16x8 vf1 = *(const bf16x8*)&vr[16 + hf * 8];
      ot[dt] = __builtin_amdgcn_mfma_f32_32x32x16_bf16(vf0, pf0, ot[dt], 0, 0, 0);
      ot[dt] = __builtin_amdgcn_mfma_f32_32x32x16_bf16(vf1, pf1, ot[dt], 0, 0, 0);
    }
    __builtin_amdgcn_s_setprio(0);
  };

  // software pipeline: stage(t+1) issued BEFORE compute(t); one barrier/tile.
  stage(0, 0);
  __syncthreads();                 // drains prologue GLDs
  int cur = 0;
  for (int j0 = 64; j0 < SL; j0 += 64) {
    stage(cur ^ 1, j0);            // prefetch next tile (lands during compute)
    compute(cur);
    __syncthreads();               // vmcnt(0)+barrier: prefetch complete, reads done
    cur ^= 1;
  }
  compute(cur);                    // last tile, no prefetch
  __syncthreads();                 // all waves done with Ks/Vs before scratch reuse

  // ---- cross-wave reduce: kw=1 waves dump partials; slot = (wv,lane) ----
  float lsum = (ls[0] + ls[1]) + (ls[2] + ls[3]);
  lsum += __shfl_xor(lsum, 32);
  // 256 slots x 36 floats (144B): wv 0,1 -> Ks area (18432B), wv 2,3 -> Vs.
  float* red = (wv < 2)
      ? (float*)&Ks[0][0] + ((wv * 64 + lane) * 36)
      : (float*)&Vs[0][0] + (((wv - 2) * 64 + lane) * 36);
  if (kw == 1) {
#pragma unroll
    for (int dt = 0; dt < 2; ++dt)
#pragma unroll
      for (int g = 0; g < 4; ++g) {
        f32x4 v;
#pragma unroll
        for (int i = 0; i < 4; ++i) v[i] = ot[dt][g * 4 + i];
        *(f32x4*)&red[dt * 16 + g * 4] = v;
      }
    red[32] = lsum;
  }
  __syncthreads();
  if (kw == 0) {
#pragma unroll
    for (int dt = 0; dt < 2; ++dt)
#pragma unroll
      for (int g = 0; g < 4; ++g) {
        f32x4 v = *(const f32x4*)&red[dt * 16 + g * 4];
#pragma unroll
        for (int i = 0; i < 4; ++i) ot[dt][g * 4 + i] += v[i];
      }
    lsum += red[32];
    const float inv = 1.f / lsum;
    float* orow = out + (((size_t)b * SL + i0 + n32) * NH + h) * DH;
#pragma unroll
    for (int dt = 0; dt < 2; ++dt)
#pragma unroll
      for (int g = 0; g < 4; ++g) {
        f32x4 v;
#pragma unroll
        for (int i = 0; i < 4; ++i) v[i] = ot[dt][g * 4 + i] * inv;
        *(f32x4*)&orow[dt * 32 + 8 * g + 4 * hf] = v;
      }
  }
}

// ---------------------------------------------------------------- launch
extern "C" void kernel_launch(void* const* d_in, const int* in_sizes, int n_in,
                              void* d_out, int out_size, void* d_ws, size_t ws_size,
                              hipStream_t stream) {
  const float* x    = (const float*)d_in[0];   // (B,L,D) fp32
  const float* w    = (const float*)d_in[1];   // (3D,D) fp32
  const float* koff = (const float*)d_in[2];   // (H,K) fp32
  const float* kamp = (const float*)d_in[3];
  const float* kshp = (const float*)d_in[4];
  float* out = (float*)d_out;                  // (B,L,D) fp32

  const size_t per = (size_t)NB * NH * SL * DH;               // 4,194,304 elems
  const size_t nx  = (size_t)NB * SL * DMODEL;                // 4,194,304
  const size_t nw  = (size_t)3 * DMODEL * DMODEL;             // 3,145,728

  __hip_bfloat16* kbuf  = (__hip_bfloat16*)d_ws;              // 8 MB
  __hip_bfloat16* vbufT = kbuf + per;                         // 8 MB
  __hip_bfloat16* qbuf  = vbufT + per;                        // 8 MB
  float* scores = (float*)(qbuf + per);                       // 256 KB
  short* xbf    = (short*)(scores + (size_t)NH * SCP);        // 8 MB
  short* wbf    = xbf + nx;                                   // 6 MB   => ~38.3 MB total

  prep_k<<<3840, 256, 0, stream>>>(x, w, koff, kamp, kshp, xbf, wbf, scores);
  qkv_gemm_k<<<dim3(48, 32), 256, 0, stream>>>(xbf, wbf, kbuf, vbufT, qbuf);
  attn_k<<<dim3(NB * NH, SL / 128), 512, 0, stream>>>(qbuf, kbuf, vbufT, scores, out);
}

// Round 12
// 168.716 us; speedup vs baseline: 1.4697x; 1.0006x over previous
//
#include <hip/hip_runtime.h>
#include <hip/hip_bf16.h>
#include <stdint.h>
#include <stddef.h>

// Problem: B=2, L=2048, D=1024, H=16, HD=64.
// Inputs FP32, output FP32.  Internal pipeline bf16 MFMA.
// R24: attn KVBLK 64->128.  Stage 128 keys per buffer, compute twice
// (ks=0,1), ONE barrier per 128 keys: barrier/drain count 32->16, prefetch
// has 2x compute to land under.  LDS 38.4->72KB x2 blocks = 144KB <= 160KB
// -> occupancy unchanged (2 blocks/CU x 8 waves, grid 512 binding).
// Bias window 256 floats (local = i_loc - j_loc + 127).  Same compute body.
// R23/R20 base (confirmed 168.8us total, attn 54.0us): 512-thread/8-wave,
// Q-tile 128, kw key-split, double-buffered stage-ahead staging, bias as
// MFMA C-init (scalar stride-1 LDS reads, conflict-free), P-assembly via
// v_cvt_pk_bf16_f32 + v_permlane32_swap_b32, exp2 with folded log2e,
// cross-wave LDS reduce.  gemm 128x64 BK=64, prep 8 elems/thread (parked;
// R15/R18/R19/R21/R22 all regressed and are reverted).

#define NB     2
#define NH     16
#define SL     2048
#define DH     64
#define DMODEL 1024
#define SCP    4096   // padded scores row stride (floats); 4095 real
#define LOG2E  1.44269504088896340736f

typedef __attribute__((ext_vector_type(8)))  short bf16x8;
typedef __attribute__((ext_vector_type(4)))  short bf16x4;
typedef __attribute__((ext_vector_type(4)))  float f32x4;
typedef __attribute__((ext_vector_type(16))) float f32x16;

static __device__ __forceinline__ short f2bf(float x) {   // RNE
  __hip_bfloat16 h = __float2bfloat16(x);
  return *reinterpret_cast<short*>(&h);
}
static __device__ __forceinline__ short f2bf_fast(float x) {  // round-half-up
  union { float f; uint32_t u; } v; v.f = x;
  return (short)((v.u + 0x8000u) >> 16);
}
static __device__ __forceinline__ float fexp2(float x) {
#if __has_builtin(__builtin_amdgcn_exp2f)
  return __builtin_amdgcn_exp2f(x);
#else
  return __expf(x * 0.69314718056f);
#endif
}
static __device__ __forceinline__ uint32_t cvtpk_bf16(float lo, float hi) {
  uint32_t r;
  asm("v_cvt_pk_bf16_f32 %0, %1, %2" : "=v"(r) : "v"(lo), "v"(hi));
  return r;
}
// swaps a's upper-32 lanes with b's lower-32 lanes (CDNA4)
#define PLSWAP(a, b) asm("v_permlane32_swap_b32 %0, %1" : "+v"(a), "+v"(b))

#define GLD(g, l) __builtin_amdgcn_global_load_lds( \
    (const __attribute__((address_space(1))) void*)(g), \
    (__attribute__((address_space(3))) void*)(l), 16, 0, 0)

// ---------------------------------------------------- prep: cvt x, cvt w, bias
// blocks: [0,2048) x-convert, [2048,3584) w-convert, [3584,3840) bias.
// 8 elems/thread (2x float4 -> bf16x8).
__global__ __launch_bounds__(256) void prep_k(
    const float* __restrict__ x, const float* __restrict__ w,
    const float* __restrict__ koff, const float* __restrict__ kamp,
    const float* __restrict__ kshp,
    short* __restrict__ xbf, short* __restrict__ wbf,
    float* __restrict__ scores) {
  const int bx = blockIdx.x, tid = threadIdx.x;
  if (bx < 3584) {
    const float* src = (bx < 2048) ? x : w;
    short* dst       = (bx < 2048) ? xbf : wbf;
    const size_t i   = ((size_t)(bx < 2048 ? bx : bx - 2048) * 256 + tid) * 8;
    float4 a = *(const float4*)(src + i);
    float4 b = *(const float4*)(src + i + 4);
    bf16x8 o;
    o[0] = f2bf(a.x); o[1] = f2bf(a.y); o[2] = f2bf(a.z); o[3] = f2bf(a.w);
    o[4] = f2bf(b.x); o[5] = f2bf(b.y); o[6] = f2bf(b.z); o[7] = f2bf(b.w);
    *(bf16x8*)(dst + i) = o;
  } else {
    const int idx = bx - 3584;
    const int h = idx >> 4;
    const int r = (idx & 15) * 256 + tid;
    if (r >= 4095) return;
    float rel = (float)(r - (SL - 1));
    float acc = 0.f;
#pragma unroll
    for (int k = 0; k < 16; ++k) {
      float o = koff[h * 16 + k];
      float a = kamp[h * 16 + k];
      float s = fabsf(kshp[h * 16 + k]);
      float d = o - rel;
      acc += a * __expf(-s * d * d);
    }
    scores[h * SCP + r] = acc * LOG2E;   // pre-scaled for exp2 in attn
  }
}

// ---------------------------------------------------------------- QKV GEMM
// (verbatim R14/R17 -- best measured config)
// C[m,n] = sum_k x[m,k] * w_in[n,k].  Tile 128x64, BK=64, 16 steps.
// Grid (48 n-tiles, 32 m-tiles) = 1536 blocks = 6/CU (LDS 24KB).
// Each n-tile = one head's 64 cols; slot = xt>>4 (0=k,1=v,2=q).
__global__ __launch_bounds__(256) void qkv_gemm_k(
    const short* __restrict__ A, const short* __restrict__ Bw,
    __hip_bfloat16* __restrict__ kbuf, __hip_bfloat16* __restrict__ vbufT,
    __hip_bfloat16* __restrict__ qbuf) {
  __shared__ __align__(16) short SM[12288];       // 24 KB; As | Bs, reused by epilogue
  short* As = SM;                                  // 128*64 shorts
  short* Bs = SM + 8192;                           // 64*64 shorts
  const int tid  = threadIdx.x;
  const int lane = tid & 63;
  const int wv   = tid >> 6;
  const int l15  = lane & 15, quad = lane >> 4;
  const int wm = (wv & 1) * 64, wn = (wv >> 1) * 32;
  const int xt = blockIdx.x, yt = blockIdx.y;
  const int m0 = yt * 128, n0 = xt * 64;
  const int which = xt >> 4;                       // 0=k, 1=v, 2=q
  const int hh    = xt & 15;                       // the head this tile serves

  f32x4 acc[4][2];
#pragma unroll
  for (int r = 0; r < 4; ++r)
#pragma unroll
    for (int c = 0; c < 2; ++c) acc[r][c] = (f32x4){0.f, 0.f, 0.f, 0.f};

  for (int kt = 0; kt < 16; ++kt) {
    const int k0 = kt * 64;
#pragma unroll
    for (int it = 0; it < 4; ++it) {               // A: 1024 chunks
      const int e8  = it * 256 + tid;
      GLD(A + (size_t)(m0 + (e8 >> 3)) * DMODEL + k0 + (e8 & 7) * 8, &As[e8 * 8]);
    }
#pragma unroll
    for (int it = 0; it < 2; ++it) {               // B: 512 chunks
      const int e8  = it * 256 + tid;
      GLD(Bw + (size_t)(n0 + (e8 >> 3)) * DMODEL + k0 + (e8 & 7) * 8, &Bs[e8 * 8]);
    }
    __syncthreads();
#pragma unroll
    for (int ki = 0; ki < 64; ki += 32) {
      bf16x8 af[4], bfv[2];
#pragma unroll
      for (int r = 0; r < 4; ++r)
        af[r] = *(const bf16x8*)&As[(wm + r * 16 + l15) * 64 + ki + quad * 8];
#pragma unroll
      for (int c = 0; c < 2; ++c)
        bfv[c] = *(const bf16x8*)&Bs[(wn + c * 16 + l15) * 64 + ki + quad * 8];
#pragma unroll
      for (int r = 0; r < 4; ++r)
#pragma unroll
        for (int c = 0; c < 2; ++c)
          acc[r][c] = __builtin_amdgcn_mfma_f32_16x16x32_bf16(af[r], bfv[c], acc[r][c], 0, 0, 0);
    }
    __syncthreads();
  }

  // ---- epilogue: C/D layout m = wm+r*16+quad*4+g, n = wn+c*16+l15 ----
  const int bb  = m0 >> 11;
  const int llb = m0 & 2047;
  if (which != 1) {
    // k/q: LDS [m][n] stride 72 -> b128 row reads -> 16B coalesced stores
    const float qs = (which == 2) ? 0.125f * LOG2E : 1.0f;  // log2e folded into q
#pragma unroll
    for (int r = 0; r < 4; ++r)
#pragma unroll
      for (int c = 0; c < 2; ++c)
#pragma unroll
        for (int gg = 0; gg < 4; ++gg)
          SM[(wm + r * 16 + quad * 4 + gg) * 72 + wn + c * 16 + l15] =
              f2bf_fast(acc[r][c][gg] * qs);
    __syncthreads();
    __hip_bfloat16* dst = (which == 0) ? kbuf : qbuf;
#pragma unroll
    for (int i = 0; i < 4; ++i) {
      const int cidx = i * 256 + tid;              // 1024 16B chunks
      const int m = cidx >> 3, ch = cidx & 7;
      bf16x8 val = *(const bf16x8*)&SM[m * 72 + ch * 8];
      *(bf16x8*)&dst[(((size_t)bb * NH + hh) * SL + llb + m) * DH + ch * 8] = val;
    }
  } else {
    // v: LDS [n][m] stride 136 -> b128 row reads -> [hd][l] 16B stores
#pragma unroll
    for (int r = 0; r < 4; ++r)
#pragma unroll
      for (int c = 0; c < 2; ++c) {
        bf16x4 pk;
#pragma unroll
        for (int gg = 0; gg < 4; ++gg) pk[gg] = f2bf_fast(acc[r][c][gg]);
        *(bf16x4*)&SM[(wn + c * 16 + l15) * 136 + wm + r * 16 + quad * 4] = pk;
      }
    __syncthreads();
#pragma unroll
    for (int i = 0; i < 4; ++i) {
      const int cidx = i * 256 + tid;              // 1024 16B chunks
      const int n = cidx >> 4, ch = cidx & 15;
      bf16x8 val = *(const bf16x8*)&SM[n * 136 + ch * 8];
      *(bf16x8*)&vbufT[(((size_t)bb * NH + hh) * DH + n) * SL + llb + ch * 8] = val;
    }
  }
}

// ---------------------------------------------------------------- attention
// R24: KVBLK=128 double-buffered (one barrier per 128 keys, compute x2).
// P-pack via v_cvt_pk_bf16_f32 + permlane32_swap; bias as MFMA C-init via
// conflict-free scalar LDS reads.  512 threads / 8 waves; Q-tile 128 rows;
// kw=w>>2 splits each 64-key half-tile.  LDS: Ks 2x18432 + Vs 2x17408 +
// Bt 2x1024 = 73728 B; 2 blocks/CU x 8 waves = 16 waves/CU.
__global__ __launch_bounds__(512, 4) void attn_k(
    const __hip_bfloat16* __restrict__ qbuf, const __hip_bfloat16* __restrict__ kbuf,
    const __hip_bfloat16* __restrict__ vbufT, const float* __restrict__ scores,
    float* __restrict__ out) {
  __shared__ __align__(16) short Ks[2][128 * 72];  // 2 x 18432 B (reduce scratch lo)
  __shared__ __align__(16) short Vs[2][64 * 136];  // 2 x 17408 B (reduce scratch hi)
  __shared__ __align__(16) float Bt[2][256];       // 2 x  1024 B  => 72 KB total
  const int bh   = blockIdx.x;
  const int b    = bh >> 4, h = bh & 15;
  const int tid  = threadIdx.x;                  // 0..511
  const int lane = tid & 63;
  const int w    = tid >> 6;                     // 0..7
  const int wv   = w & 3;                        // q-row group (rows wv*32..+31)
  const int kw   = w >> 2;                       // key half within each 64-key subtile
  const int n32  = lane & 31, hf = lane >> 5;
  const int i0b  = blockIdx.y * 128;
  const int i0   = i0b + wv * 32;
  const __hip_bfloat16* qb = qbuf + (size_t)bh * SL * DH;
  const short* kb = (const short*)(kbuf + (size_t)bh * SL * DH);
  const short* vb = (const short*)(vbufT + (size_t)bh * DH * SL);
  const float* sc = scores + h * SCP;

  bf16x8 qf[4];
#pragma unroll
  for (int kc = 0; kc < 4; ++kc)
    qf[kc] = *(const bf16x8*)&qb[(size_t)(i0 + n32) * DH + kc * 16 + hf * 8];

  f32x16 ot[2];    // O^T partial: hd = dt*32 + (r&3)+8*(r>>2)+4*hf, qrow = n32
#pragma unroll
  for (int dt = 0; dt < 2; ++dt)
#pragma unroll
    for (int r = 0; r < 16; ++r) ot[dt][r] = 0.f;
  float ls[4] = {0.f, 0.f, 0.f, 0.f};

  // stage 128-key tile at offset j0 into buffer bsel (K, V, 256-float bias)
  auto stage = [&](int bsel, int j0) {
    const short* ksrc = kb + (size_t)j0 * DH;
#pragma unroll
    for (int i = 0; i < 2; ++i) {                // K: 1152 chunks over 512 thr
      int c = i * 512 + tid; int r = c / 9, s = c - r * 9;
      GLD(ksrc + (size_t)r * DH + s * 8, &Ks[bsel][c * 8]);
    }
    if (tid < 128) {
      int c = 1024 + tid; int r = c / 9, s = c - r * 9;
      GLD(ksrc + (size_t)r * DH + s * 8, &Ks[bsel][c * 8]);
    }
#pragma unroll
    for (int i = 0; i < 2; ++i) {                // V: 1088 chunks (17/row)
      int c = i * 512 + tid; int r = c / 17, s = c - r * 17;
      GLD(vb + (size_t)r * SL + j0 + s * 8, &Vs[bsel][c * 8]);
    }
    if (tid < 64) {
      int c = 1024 + tid; int r = c / 17, s = c - r * 17;
      GLD(vb + (size_t)r * SL + j0 + s * 8, &Vs[bsel][c * 8]);
    }
    // bias window: (i-j)+2047 for i_loc,j_loc in [0,128) spans
    // [i0b-j0+1920, i0b-j0+2174]; 256 floats = 64 chunks
    if (tid < 64) GLD(sc + (i0b - j0 + 1920) + tid * 4, &Bt[bsel][tid * 4]);
  };

  // compute one 64-key half (ks=0,1) of the staged 128-key tile
  auto compute = [&](int bsel, int ks) {
    const short* Kp = Ks[bsel];
    const short* Vp = Vs[bsel];
    const float* Bp = Bt[bsel];
    const int koffs = ks * 64 + kw * 32;         // this wave's 32 keys
    // bias preloaded as MFMA C operand: local idx (i_loc - j_loc) + 127
    // (scalar stride-1 reads: lanes hit consecutive floats, conflict-free)
    f32x16 st;
    const int tb0 = wv * 32 + n32 - koffs - 4 * hf + 127;
#pragma unroll
    for (int g = 0; g < 4; ++g)
#pragma unroll
      for (int i = 0; i < 4; ++i) st[g * 4 + i] = Bp[tb0 - 8 * g - i];
    __builtin_amdgcn_s_setprio(1);
#pragma unroll
    for (int kc = 0; kc < 4; ++kc) {
      bf16x8 kf = *(const bf16x8*)&Kp[(koffs + n32) * 72 + kc * 16 + hf * 8];
      st = __builtin_amdgcn_mfma_f32_32x32x16_bf16(kf, qf[kc], st, 0, 0, 0);
    }
    __builtin_amdgcn_s_setprio(0);
    // softmax numerator + P-fragment assembly (all-VALU, no LDS):
    float pv[16];
#pragma unroll
    for (int g = 0; g < 4; ++g)
#pragma unroll
      for (int i = 0; i < 4; ++i) {
        pv[g * 4 + i] = fexp2(st[g * 4 + i]);
        ls[g] += pv[g * 4 + i];
      }
    uint32_t a0 = cvtpk_bf16(pv[0],  pv[1]),  a1 = cvtpk_bf16(pv[2],  pv[3]);
    uint32_t b0 = cvtpk_bf16(pv[4],  pv[5]),  b1 = cvtpk_bf16(pv[6],  pv[7]);
    uint32_t c0 = cvtpk_bf16(pv[8],  pv[9]),  c1 = cvtpk_bf16(pv[10], pv[11]);
    uint32_t d0 = cvtpk_bf16(pv[12], pv[13]), d1 = cvtpk_bf16(pv[14], pv[15]);
    PLSWAP(a0, b0); PLSWAP(a1, b1);            // pf0 = {a0,a1,b0,b1}
    PLSWAP(c0, d0); PLSWAP(c1, d1);            // pf1 = {c0,c1,d0,d1}
    union { uint32_t u[4]; bf16x8 v; } P0, P1;
    P0.u[0] = a0; P0.u[1] = a1; P0.u[2] = b0; P0.u[3] = b1;
    P1.u[0] = c0; P1.u[1] = c1; P1.u[2] = d0; P1.u[3] = d1;
    const bf16x8 pf0 = P0.v, pf1 = P1.v;
    __builtin_amdgcn_s_setprio(1);
#pragma unroll
    for (int dt = 0; dt < 2; ++dt) {
      const short* vr = &Vp[(dt * 32 + n32) * 136 + koffs];
      bf16x8 vf0 = *(const bf16x8*)&vr[hf * 8];
      bf16x8 vf1 = *(const bf16x8*)&vr[16 + hf * 8];
      ot[dt] = __builtin_amdgcn_mfma_f32_32x32x16_bf16(vf0, pf0, ot[dt], 0, 0, 0);
      ot[dt] = __builtin_amdgcn_mfma_f32_32x32x16_bf16(vf1, pf1, ot[dt], 0, 0, 0);
    }
    __builtin_amdgcn_s_setprio(0);
  };

  // software pipeline: stage(t+1) issued BEFORE compute(t); one barrier/128 keys.
  stage(0, 0);
  __syncthreads();                 // drains prologue GLDs
  int cur = 0;
  for (int j0 = 128; j0 < SL; j0 += 128) {
    stage(cur ^ 1, j0);            // prefetch next tile (lands during 2x compute)
    compute(cur, 0);
    compute(cur, 1);
    __syncthreads();               // vmcnt(0)+barrier: prefetch complete, reads done
    cur ^= 1;
  }
  compute(cur, 0);                 // last tile, no prefetch
  compute(cur, 1);
  __syncthreads();                 // all waves done with Ks/Vs before scratch reuse

  // ---- cross-wave reduce: kw=1 waves dump partials; slot = (wv,lane) ----
  float lsum = (ls[0] + ls[1]) + (ls[2] + ls[3]);
  lsum += __shfl_xor(lsum, 32);
  // 256 slots x 36 floats (144B): wv 0,1 -> Ks area (18432B each), wv 2,3 -> Vs.
  float* red = (wv < 2)
      ? (float*)&Ks[0][0] + ((wv * 64 + lane) * 36)
      : (float*)&Vs[0][0] + (((wv - 2) * 64 + lane) * 36);
  if (kw == 1) {
#pragma unroll
    for (int dt = 0; dt < 2; ++dt)
#pragma unroll
      for (int g = 0; g < 4; ++g) {
        f32x4 v;
#pragma unroll
        for (int i = 0; i < 4; ++i) v[i] = ot[dt][g * 4 + i];
        *(f32x4*)&red[dt * 16 + g * 4] = v;
      }
    red[32] = lsum;
  }
  __syncthreads();
  if (kw == 0) {
#pragma unroll
    for (int dt = 0; dt < 2; ++dt)
#pragma unroll
      for (int g = 0; g < 4; ++g) {
        f32x4 v = *(const f32x4*)&red[dt * 16 + g * 4];
#pragma unroll
        for (int i = 0; i < 4; ++i) ot[dt][g * 4 + i] += v[i];
      }
    lsum += red[32];
    const float inv = 1.f / lsum;
    float* orow = out + (((size_t)b * SL + i0 + n32) * NH + h) * DH;
#pragma unroll
    for (int dt = 0; dt < 2; ++dt)
#pragma unroll
      for (int g = 0; g < 4; ++g) {
        f32x4 v;
#pragma unroll
        for (int i = 0; i < 4; ++i) v[i] = ot[dt][g * 4 + i] * inv;
        *(f32x4*)&orow[dt * 32 + 8 * g + 4 * hf] = v;
      }
  }
}

// ---------------------------------------------------------------- launch
extern "C" void kernel_launch(void* const* d_in, const int* in_sizes, int n_in,
                              void* d_out, int out_size, void* d_ws, size_t ws_size,
                              hipStream_t stream) {
  const float* x    = (const float*)d_in[0];   // (B,L,D) fp32
  const float* w    = (const float*)d_in[1];   // (3D,D) fp32
  const float* koff = (const float*)d_in[2];   // (H,K) fp32
  const float* kamp = (const float*)d_in[3];
  const float* kshp = (const float*)d_in[4];
  float* out = (float*)d_out;                  // (B,L,D) fp32

  const size_t per = (size_t)NB * NH * SL * DH;               // 4,194,304 elems
  const size_t nx  = (size_t)NB * SL * DMODEL;                // 4,194,304
  const size_t nw  = (size_t)3 * DMODEL * DMODEL;             // 3,145,728

  __hip_bfloat16* kbuf  = (__hip_bfloat16*)d_ws;              // 8 MB
  __hip_bfloat16* vbufT = kbuf + per;                         // 8 MB
  __hip_bfloat16* qbuf  = vbufT + per;                        // 8 MB
  float* scores = (float*)(qbuf + per);                       // 256 KB
  short* xbf    = (short*)(scores + (size_t)NH * SCP);        // 8 MB
  short* wbf    = xbf + nx;                                   // 6 MB   => ~38.3 MB total

  prep_k<<<3840, 256, 0, stream>>>(x, w, koff, kamp, kshp, xbf, wbf, scores);
  qkv_gemm_k<<<dim3(48, 32), 256, 0, stream>>>(xbf, wbf, kbuf, vbufT, qbuf);
  attn_k<<<dim3(NB * NH, SL / 128), 512, 0, stream>>>(qbuf, kbuf, vbufT, scores, out);
}